// Round 9
// baseline (364226.758 us; speedup 1.0000x reference)
//
#include <hip/hip_runtime.h>
#include <math.h>

#define NWG   512          // 2 WGs per CU -- per-WG weights fit on-chip
#define TPB   512          // 8 waves
#define H     1536
#define S_TOT 2048
#define RPW   3            // h rows owned per WG
#define GRW   12           // gate rows per WG (4 gates x 3 rows)
#define NLW   8            // W_ih1 local rows 0..7 kept in LDS (8..11 in regs)
#define OUTP  2048         // probs offset in d_out

struct Params {
  const float* __restrict__ inputs; const float* __restrict__ h_init;
  const float* __restrict__ c_init;
  const float* __restrict__ W_ih0; const float* __restrict__ W_hh0;
  const float* __restrict__ b_ih0; const float* __restrict__ b_hh0;
  const float* __restrict__ W_ih1; const float* __restrict__ W_hh1;
  const float* __restrict__ b_ih1; const float* __restrict__ b_hh1;
  const float* __restrict__ W_lin; const float* __restrict__ b_lin;
  const float* __restrict__ lookup;
  float* __restrict__ out; float* __restrict__ h0g; float* __restrict__ h1g;
  unsigned* __restrict__ bar;
};

__device__ __forceinline__ float gload(const float* p) {
  return __hip_atomic_load(p, __ATOMIC_RELAXED, __HIP_MEMORY_SCOPE_AGENT);
}
__device__ __forceinline__ void gstore(float* p, float v) {
  __hip_atomic_store(p, v, __ATOMIC_RELAXED, __HIP_MEMORY_SCOPE_AGENT);
}

// JAX threefry2x32 (20 rounds), bit-exact.
__device__ __forceinline__ void tf2x32(unsigned k0, unsigned k1,
                                       unsigned x0, unsigned x1,
                                       unsigned& o0, unsigned& o1) {
  unsigned ks2 = k0 ^ k1 ^ 0x1BD11BDAu;
  x0 += k0; x1 += k1;
#define TFR(r) { x0 += x1; x1 = ((x1 << r) | (x1 >> (32 - r))); x1 ^= x0; }
  TFR(13) TFR(15) TFR(26) TFR(6)   x0 += k1;  x1 += ks2 + 1u;
  TFR(17) TFR(29) TFR(16) TFR(24)  x0 += ks2; x1 += k0 + 2u;
  TFR(13) TFR(15) TFR(26) TFR(6)   x0 += k0;  x1 += k1 + 3u;
  TFR(17) TFR(29) TFR(16) TFR(24)  x0 += k1;  x1 += ks2 + 4u;
  TFR(13) TFR(15) TFR(26) TFR(6)   x0 += ks2; x1 += k0 + 5u;
#undef TFR
  o0 = x0; o1 = x1;
}

__device__ __forceinline__ double bsum64(double v) {
#pragma unroll
  for (int o = 32; o > 0; o >>= 1) v += __shfl_xor(v, o);
  return v;
}

__device__ __forceinline__ float sigf(float x) { return 1.0f / (1.0f + expf(-x)); }

// INIT-ONLY all-to-all flag barrier (poison-tolerant, 512 flags: 64 lanes x 8).
__device__ __forceinline__ void flagbar(unsigned* bar, unsigned e, int tid, int wg) {
  __builtin_amdgcn_fence(__ATOMIC_RELEASE, "agent");
  __syncthreads();      // everyone's data published before flag
  if (tid == 0)
    __hip_atomic_store(&bar[wg], e, __ATOMIC_RELEASE, __HIP_MEMORY_SCOPE_AGENT);
  if (tid < 64) {
    const unsigned* f = bar + tid * 8;
    bool done;
    do {
      int dd = 0;
#pragma unroll
      for (int i = 0; i < 8; ++i)
        dd |= (int)(__hip_atomic_load(f + i, __ATOMIC_RELAXED, __HIP_MEMORY_SCOPE_AGENT) - e);
      done = (dd >= 0);   // all deltas >= 0
    } while (!__all(done));
    __builtin_amdgcn_fence(__ATOMIC_ACQUIRE, "agent");
  }
  __syncthreads();
}

// Steady-state barrier: single arrival counter + s_sleep poll backoff.
// target monotone (+NWG per barrier); run-ahead safe.
__device__ __forceinline__ void cntbar(unsigned* cnt, unsigned target, int tid) {
  __builtin_amdgcn_fence(__ATOMIC_RELEASE, "agent");
  __syncthreads();      // everyone's data published before arrival
  if (tid == 0)
    (void)__hip_atomic_fetch_add(cnt, 1u, __ATOMIC_RELEASE, __HIP_MEMORY_SCOPE_AGENT);
  if (tid < 64) {
    for (;;) {
      unsigned c = __hip_atomic_load(cnt, __ATOMIC_RELAXED, __HIP_MEMORY_SCOPE_AGENT);
      if ((int)(c - target) >= 0) break;
      __builtin_amdgcn_s_sleep(4);   // ~256 clk backoff
    }
    __builtin_amdgcn_fence(__ATOMIC_ACQUIRE, "agent");
  }
  __syncthreads();
}

// ROUND-9 STRATEGY: rounds 0-8 proved (a) the allocator pins VGPRs at 128
// for TPB=512 no matter what, (b) scratch spills reload from HBM (~108 GB),
// (c) streamed weights are NOT L3-retained (round 8: FETCH went UP to 122 GB
// at 1.5 TB/s effective). Same wall both ways: 442 KB/WG of weights re-read
// per step from beyond-L2. Fix the FOOTPRINT instead: NWG=512 (2 WGs/CU),
// RPW=3 -> 221 KB/WG = 24 rows in REGISTERS (96 floats/thread, fits the 128
// budget that the allocator insists on -- it was sized for 2 blocks/CU all
// along) + 8 rows in LDS (62 KB/WG total, 124 KB/CU). Zero steady-state
// weight traffic. W_lin moves to per-step global reads (shared -> L2-hot).
// Occupancy doubles to 16 waves/CU. amdgpu_waves_per_eu(4) caps VGPR at
// 512/4=128 ensuring 2-WG co-residency (barrier liveness).
__global__ __launch_bounds__(TPB)
__attribute__((amdgpu_waves_per_eu(4)))
void lstm_persistent(Params P) {
  const int tid  = threadIdx.x;
  const int wg   = blockIdx.x;
  const int wv   = tid >> 6;      // 0..7
  const int lane = tid & 63;

  // ---- LDS (~62 KB/WG; 2 WGs/CU = ~124 KB/CU <= 160) ----
  __shared__ float s_W1[NLW * H];      // W_ih1 local rows 0..7  (49.2 KB)
  __shared__ float s_Wih0[GRW * 32];   // 1.5 KB
  __shared__ float s_h0[H], s_h1[H];   // 12 KB
  __shared__ float s_bih0[GRW], s_bhh0[GRW], s_bih1[GRW], s_bhh1[GRW];
  __shared__ float s_hh1dot[GRW], s_gate[GRW];
  __shared__ float s_x[32];
  __shared__ float s_c0[RPW], s_c1[RPW];
  __shared__ float s_logits[16];
  __shared__ float s_blin[10], s_lookup[10];
  __shared__ int   s_action;

  // flags occupy bar[0..511]; counter on its own cacheline at bar[640]
  unsigned* cnt = P.bar + 640;

  // ---------------- init ----------------
  if (wg == 0 && tid == 0)
    __hip_atomic_store(cnt, 0u, __ATOMIC_RELAXED, __HIP_MEMORY_SCOPE_AGENT);
  for (int k = tid; k < GRW * 32; k += TPB) {
    int idx = k >> 5, kk = k & 31;
    int q = idx / RPW, u = idx % RPW;
    int gr = q * H + wg * RPW + u;
    s_Wih0[k] = P.W_ih0[gr * 32 + kk];
  }
  for (int k = tid; k < NLW * H; k += TPB) {
    int r = k / H, col = k % H;          // W_ih1 local row r (0..7)
    int q = r / RPW, u = r % RPW;
    int gr = q * H + wg * RPW + u;
    s_W1[k] = P.W_ih1[(size_t)gr * H + col];
  }
  if (tid < GRW) {
    int q = tid / RPW, u = tid % RPW;
    int gr = q * H + wg * RPW + u;
    s_bih0[tid] = P.b_ih0[gr]; s_bhh0[tid] = P.b_hh0[gr];
    s_bih1[tid] = P.b_ih1[gr]; s_bhh1[tid] = P.b_hh1[gr];
  }
  if (tid < 10) { s_blin[tid] = P.b_lin[tid]; s_lookup[tid] = P.lookup[tid]; }
  if (tid < RPW) {
    s_c0[tid] = P.c_init[wg * RPW + tid];
    s_c1[tid] = P.c_init[H + wg * RPW + tid];
    gstore(P.h0g + wg * RPW + tid, P.h_init[wg * RPW + tid]);
    gstore(P.h1g + wg * RPW + tid, P.h_init[H + wg * RPW + tid]);
  }

  // Register weights: 96 floats/thread, fits the 128-VGPR budget.
  // wrA[3]: phase-1 dots d = wv*3+sl (d<12: W_hh0 local row d vs h0;
  //         d>=12: W_hh1 local row d-12 vs h1). 3 | 12, so per-wave uniform.
  // wrB:    phase-2 W_ih1 local row 8+wv (waves 0-3 only; rows 0-7 in LDS).
  float wrA[3][24];
  float wrB[24];
  {
    const float* srcA = (wv < 4) ? P.W_hh0 : P.W_hh1;
    int base = (wv < 4) ? wv * 3 : (wv - 4) * 3;   // local row of srcA
#pragma unroll
    for (int sl = 0; sl < 3; ++sl) {
      int lidx = base + sl;
      int q = lidx / RPW, u = lidx % RPW;
      int gr = q * H + wg * RPW + u;
      const float* rp = srcA + (size_t)gr * H;
#pragma unroll
      for (int t = 0; t < 24; ++t) wrA[sl][t] = rp[lane + (t << 6)];
    }
    if (wv < 4) {
      int lidx = 8 + wv;
      int q = lidx / RPW, u = lidx % RPW;
      int gr = q * H + wg * RPW + u;
      const float* rp = P.W_ih1 + (size_t)gr * H;
#pragma unroll
      for (int t = 0; t < 24; ++t) wrB[t] = rp[lane + (t << 6)];
    } else {
#pragma unroll
      for (int t = 0; t < 24; ++t) wrB[t] = 0.0f;
    }
  }

  flagbar(P.bar, 1u, tid, wg);   // init barrier (poison-tolerant, publishes cnt=0)
  unsigned bt = 0;               // counter-barrier target

  // ---------------- main sequential loop ----------------
  for (int s = 0; s <= S_TOT; ++s) {
    // stage h0prev / h1prev
#pragma unroll
    for (int r = 0; r < 3; ++r) {
      int k = tid + r * TPB;
      s_h0[k] = gload(P.h0g + k);
      s_h1[k] = gload(P.h1g + k);
    }
    __syncthreads();

    if (s > 0) {
      int sp = s - 1;
      // logits = h1prev @ W_lin.T + b_lin (redundant per WG, fp64 acc;
      // W_lin streamed from global -- shared across WGs, L2-resident)
#pragma unroll
      for (int p2 = 0; p2 < 2; ++p2) {
        int l = wv + 8 * p2;
        if (l < 10) {
          const float* wl = P.W_lin + l * H;
          double acc = 0.0;
#pragma unroll
          for (int t = 0; t < 24; ++t) {
            int off = lane + (t << 6);
            acc += (double)wl[off] * (double)s_h1[off];
          }
          acc = bsum64(acc);
          if (lane == 0) s_logits[l] = __fadd_rn((float)acc, s_blin[l]);
        }
      }
      __syncthreads();

      if (wv == 0) {
        // key_sp = threefry(key(42)=(0,42); 0, sp)   [partitionable split]
        unsigned kk0, kk1; tf2x32(0u, 42u, 0u, (unsigned)sp, kk0, kk1);
        unsigned b1, b2; tf2x32(kk0, kk1, 0u, (unsigned)lane, b1, b2);
        unsigned bits = b1 ^ b2;
        float uraw = __fsub_rn(__uint_as_float((bits >> 9) | 0x3F800000u), 1.0f);
        const float TINY = 1.17549435e-38f;
        float u  = fmaxf(TINY, __fadd_rn(uraw, TINY));
        float gum = -logf(-logf(u));
        float lg = (lane < 10) ? s_logits[lane] : 0.0f;
        float y  = (lane < 10) ? __fadd_rn(lg, gum) : -INFINITY;
        int ai = lane;
#pragma unroll
        for (int o = 1; o < 16; o <<= 1) {
          float oy = __shfl_xor(y, o); int oi = __shfl_xor(ai, o);
          if (oy > y || (oy == y && oi < ai)) { y = oy; ai = oi; }
        }
        float lm = (lane < 10) ? lg : -INFINITY;
#pragma unroll
        for (int o = 1; o < 16; o <<= 1) lm = fmaxf(lm, __shfl_xor(lm, o));
        float e2 = (lane < 10) ? expf(__fsub_rn(lg, lm)) : 0.0f;
        float ssum = e2;
#pragma unroll
        for (int o = 1; o < 16; o <<= 1) ssum = __fadd_rn(ssum, __shfl_xor(ssum, o));
        if (lane == 0) s_action = ai;
        if (wg == 0) {
          if (lane < 10) P.out[OUTP + sp * 10 + lane] = e2 / ssum;
          if (lane == 0) P.out[sp] = (float)ai;
        }
      }
      __syncthreads();
      if (tid == 0) {
        int jp = sp & 31;
        if (jp != 0) s_x[jp] = __fmul_rn(s_x[jp], s_lookup[s_action]);
      }
      __syncthreads();
    }

    if (s == S_TOT) break;
    int ii = s >> 5, jj = s & 31;
    if (jj == 0 && tid < 32) s_x[tid] = P.inputs[ii * 32 + tid];
    __syncthreads();

    // ---------- phase 1: waves 0-3: gates0 dots (W_hh0 rows 0-11 vs h0,
    //            + W_ih0*x + biases); waves 4-7: W_hh1 rows 0-11 vs h1 ----------
    {
      const float* hp = (wv < 4) ? s_h0 : s_h1;
      double a0 = 0, a1 = 0, a2 = 0;
#pragma unroll
      for (int t = 0; t < 24; ++t) {
        int off = lane + (t << 6);
        double hv = (double)hp[off];
        a0 += (double)wrA[0][t] * hv;
        a1 += (double)wrA[1][t] * hv;
        a2 += (double)wrA[2][t] * hv;
      }
      a0 = bsum64(a0); a1 = bsum64(a1); a2 = bsum64(a2);
      if (wv < 4) {
        double xa[3];
#pragma unroll
        for (int sl = 0; sl < 3; ++sl) {
          int d = wv * 3 + sl;
          double pp = (lane < 32)
            ? (double)s_Wih0[(d << 5) + lane] * (double)s_x[lane] : 0.0;
#pragma unroll
          for (int o = 16; o > 0; o >>= 1) pp += __shfl_xor(pp, o);
          xa[sl] = pp;
        }
        if (lane == 0) {
          double aa[3] = {a0, a1, a2};
#pragma unroll
          for (int sl = 0; sl < 3; ++sl) {
            int d = wv * 3 + sl;
            s_gate[d] = __fadd_rn(__fadd_rn(__fadd_rn((float)xa[sl], s_bih0[d]),
                                            (float)aa[sl]), s_bhh0[d]);
          }
        }
      } else {
        if (lane == 0) {
          double aa[3] = {a0, a1, a2};
#pragma unroll
          for (int sl = 0; sl < 3; ++sl) {
            int d = (wv - 4) * 3 + sl;
            s_hh1dot[d] = (float)aa[sl];
          }
        }
      }
    }
    __syncthreads();
    if (tid < RPW) {
      int u = tid;
      float gi = s_gate[u], gf = s_gate[3 + u], gg = s_gate[6 + u], go = s_gate[9 + u];
      float c = __fadd_rn(__fmul_rn(sigf(gf), s_c0[u]), __fmul_rn(sigf(gi), tanhf(gg)));
      s_c0[u] = c;
      float h = __fmul_rn(sigf(go), tanhf(c));
      gstore(P.h0g + wg * RPW + u, h);
    }
    bt += NWG; cntbar(cnt, bt, tid);

    // ---------- phase 2: gates1 = W_ih1*h0 + stashed hh1dot ----------
#pragma unroll
    for (int r = 0; r < 3; ++r) {
      int k = tid + r * TPB;
      s_h0[k] = gload(P.h0g + k);
    }
    __syncthreads();
    {
      // LDS rows 0..7: wave w does local row w
      double aL = 0;
#pragma unroll
      for (int t = 0; t < 24; ++t) {
        int off = lane + (t << 6);
        aL += (double)s_W1[wv * H + off] * (double)s_h0[off];
      }
      aL = bsum64(aL);
      if (lane == 0) {
        int d = wv;
        s_gate[d] = __fadd_rn(__fadd_rn(__fadd_rn((float)aL, s_bih1[d]),
                                        s_hh1dot[d]), s_bhh1[d]);
      }
      // register rows 8..11: waves 0-3
      if (wv < 4) {
        double aR = 0;
#pragma unroll
        for (int t = 0; t < 24; ++t) {
          int off = lane + (t << 6);
          aR += (double)wrB[t] * (double)s_h0[off];
        }
        aR = bsum64(aR);
        if (lane == 0) {
          int d = 8 + wv;
          s_gate[d] = __fadd_rn(__fadd_rn(__fadd_rn((float)aR, s_bih1[d]),
                                          s_hh1dot[d]), s_bhh1[d]);
        }
      }
    }
    __syncthreads();
    if (tid < RPW) {
      int u = tid;
      float gi = s_gate[u], gf = s_gate[3 + u], gg = s_gate[6 + u], go = s_gate[9 + u];
      float c = __fadd_rn(__fmul_rn(sigf(gf), s_c1[u]), __fmul_rn(sigf(gi), tanhf(gg)));
      s_c1[u] = c;
      float h = __fmul_rn(sigf(go), tanhf(c));
      gstore(P.h1g + wg * RPW + u, h);
    }
    bt += NWG; cntbar(cnt, bt, tid);
  }
}

extern "C" void kernel_launch(void* const* d_in, const int* in_sizes, int n_in,
                              void* d_out, int out_size, void* d_ws, size_t ws_size,
                              hipStream_t stream) {
  (void)in_sizes; (void)n_in; (void)out_size; (void)ws_size;
  Params p;
  p.inputs = (const float*)d_in[0];
  p.h_init = (const float*)d_in[1];
  p.c_init = (const float*)d_in[2];
  p.W_ih0  = (const float*)d_in[3];
  p.W_hh0  = (const float*)d_in[4];
  p.b_ih0  = (const float*)d_in[5];
  p.b_hh0  = (const float*)d_in[6];
  p.W_ih1  = (const float*)d_in[7];
  p.W_hh1  = (const float*)d_in[8];
  p.b_ih1  = (const float*)d_in[9];
  p.b_hh1  = (const float*)d_in[10];
  p.W_lin  = (const float*)d_in[11];
  p.b_lin  = (const float*)d_in[12];
  p.lookup = (const float*)d_in[13];
  p.out    = (float*)d_out;
  float* ws = (float*)d_ws;
  p.h0g = ws;
  p.h1g = ws + H;
  p.bar = (unsigned*)(ws + 2 * H);

  hipLaunchKernelGGL(lstm_persistent, dim3(NWG), dim3(TPB), 0, stream, p);
}